// Round 4
// baseline (550.666 us; speedup 1.0000x reference)
//
#include <hip/hip_runtime.h>
#include <stdint.h>

typedef __bf16 bf16;
typedef __bf16 bf16x4 __attribute__((ext_vector_type(4)));
typedef __bf16 bf16x8 __attribute__((ext_vector_type(8)));
typedef float  f32x4  __attribute__((ext_vector_type(4)));
typedef float  fvec4  __attribute__((ext_vector_type(4)));

#define B_DIM 16384
#define H_DIM 1024
#define K_DIM 2048
#define NKT   32      // K_DIM / 64 K-tiles

// ---- async global->LDS, 16B per lane ----
__device__ __forceinline__ void g2l16(const void* g, void* l) {
    __builtin_amdgcn_global_load_lds(
        (const __attribute__((address_space(1))) void*)g,
        (__attribute__((address_space(3))) void*)l,
        16, 0, 0);
}

__device__ __forceinline__ float sigm_fast(float x) {
    x = fminf(fmaxf(x, -40.f), 40.f);
    float e = __builtin_amdgcn_exp2f(-1.4426950408889634f * x);
    return __builtin_amdgcn_rcpf(1.0f + e);
}
__device__ __forceinline__ float tanh_fast(float x) {
    x = fminf(fmaxf(x, -40.f), 40.f);
    float e = __builtin_amdgcn_exp2f(-2.8853900817779268f * x);   // exp(-2x)
    return (1.0f - e) * __builtin_amdgcn_rcpf(1.0f + e);
}

// ---- streaming convert, REWRITTEN: dense 16B/lane loads (no NT, no stride) ----
// Old version: 32B/lane = 2x dwordx4 at stride 32 + nontemporal -> each instr
// uses 16B of every 32B with no cache fill = read amplification (~230us vs
// 43us roofline suspected). New: lane i loads floats [4i,4i+4) of a row
// (fully dense per instruction), stores 4 bf16 (8B, dense). 4 rows per block.
// blocks [0,4096): x -> U[:, 0:1024]     | [4096,8192): h -> U[:, 1024:2048]
// [8192,9216): Wx -> W[:, 0:1024]        | [9216,10240): Rh -> W[:, 1024:2048]
__global__ __launch_bounds__(256) void cvt_all(const float* __restrict__ x,
                                               const float* __restrict__ h,
                                               const float* __restrict__ Wx,
                                               const float* __restrict__ Rh,
                                               const float* __restrict__ bx,
                                               const float* __restrict__ bh,
                                               bf16* __restrict__ U,
                                               bf16* __restrict__ W,
                                               float* __restrict__ bb) {
    const int b   = blockIdx.x;          // 0..10239
    const int tid = threadIdx.x;
    const float* src;
    bf16* dst;
    int half, blk;
    if (b < 8192) {                      // x / h  -> U (16384 rows)
        src  = (b < 4096) ? x : h;
        half = (b < 4096) ? 0 : 1024;
        dst  = U;
        blk  = b & 4095;                 // 4096 blocks x 4 rows = 16384 rows
    } else {                             // Wx / Rh -> W (4096 rows)
        int wb = b - 8192;
        src  = (wb < 1024) ? Wx : Rh;
        half = (wb < 1024) ? 0 : 1024;
        dst  = W;
        blk  = wb & 1023;                // 1024 blocks x 4 rows = 4096 rows
    }
    const float* s0 = src + (((size_t)blk << 2) << 10) + (tid << 2);   // row=4*blk, col=4*tid
    bf16*        d0 = dst + (((size_t)blk << 2) << 11) + half + (tid << 2);
#pragma unroll
    for (int u = 0; u < 4; ++u) {
        fvec4 v = *(const fvec4*)(s0 + (u << 10));                     // next src row
        bf16x4 o = {(bf16)v.x, (bf16)v.y, (bf16)v.z, (bf16)v.w};
        *(bf16x4*)(d0 + (u << 11)) = o;                                // next dst row
    }
    if (b == 0) {
        for (int i = tid; i < 4096; i += 256) bb[i] = bx[i] + bh[i];
    }
}

// ---- fused GEMM (pre = U.W^T + bb) + LSTM epilogue, 4-barrier 256^2 schedule ----
// BM=BN=256, BK=64, 8 waves (2M x 4N), per-wave 128x64 out (acc[8][4] f32x4).
// B tile row r -> gate (r>>4)&3, h_local (r>>6)*16+(r&15): wave wn holds all 4
// gates for h = h0 + wn*16 + lc => lane-local LSTM epilogue (ni == gate).
// LDS: As/Bs[2 dbuf][256x64] = 128 KiB; XOR chunk-swizzle c^(row&7) via
// pre-swizzled GLOBAL source (global_load_lds dest must be linear).
//
// v2 schedule: ONE barrier per phase (4/kt, was 8), NO manual lgkmcnt(0)
// (compiler inserts counted dataflow waits -> ds_reads fly across barriers
// into the MFMA clusters instead of serializing LDS pipe vs MFMA pipe).
//   P1: BAR | stage kt+1.A-hi | read a0(8)+b all(8) | Q(0,0) [b2,b3 in flight]
//   P2: BAR | stage kt+1.B-hi | Q(0,2)              | read a1(8) [fly into P3]
//   P3: BAR | stage kt+2.B-lo | Q(4,0)
//   P4: BAR | stage kt+2.A-lo | Q(4,2) | vmcnt(4)  [never 0 mid-loop]
// WAR safety: every staged region's readers complete (compiler lgkm wait
// precedes their consuming MFMA, which precedes that wave's next barrier)
// before the barrier that precedes the stage:
//   P1 stage A-hi(buf^1): read kt-1 by wm1, done < kt-1.P3 wait < BAR_P1(kt)
//   P2 stage B-hi(buf^1): read kt-1 P1/P2, done < BAR_P2(kt)
//   P3 stage B-lo(buf):   b reads done < Q(0,2)@P2 < BAR_P3
//   P4 stage A-lo(buf):   a0 done < Q(0,2)@P2; a1 done < Q(4,0)@P3 < BAR_P4
// RAW safety: vmcnt(4) at P4-end leaves exactly {ktP3,ktP4} outstanding,
// draining {kt-1.P3,P4, kt.P1,P2} = the 4 half-tiles kt+1 reads; BAR_P1(kt+1)
// makes the drain collective. Prologue ends with the same invariant.
// Tail: kt==30 drains vmcnt(0); kt==31 computes only.
__global__ __launch_bounds__(512, 2)
void lstm_fused(const bf16* __restrict__ U, const bf16* __restrict__ W,
                const float* __restrict__ bb, const float* __restrict__ cprev,
                float* __restrict__ out) {
    __shared__ __align__(16) bf16 As[2][256 * 64];
    __shared__ __align__(16) bf16 Bs[2][256 * 64];

    const int tid  = threadIdx.x;
    const int wave = tid >> 6;
    const int lane = tid & 63;
    const int quad = lane >> 4;
    const int lc   = lane & 15;
    const int wm   = wave >> 2;          // 0..1  (M half)
    const int wn   = wave & 3;           // 0..3  (N quarter)

    // XCD-aware mapping: 1024 blocks, 8 XCDs x 128. Each XCD owns 2 h-slices
    // and sweeps all 64 m-tiles -> B panel hot in XCD-L2, U shared via L3.
    int bid   = blockIdx.x;
    int xcd   = bid & 7;
    int t     = bid >> 3;                // 0..127
    int h_idx = (xcd << 1) + (t >> 6);   // 0..15
    int m_idx = t & 63;                  // 0..63
    const int m0 = m_idx << 8;           // 256 U-rows per tile
    const int h0 = h_idx << 6;           // 64 h per tile

    // ---- per-thread staging addresses (32-bit offsets: U=64MiB, W=16MiB) ----
    uint32_t offA[2][2], offB[2][2];     // [ld][half]
    uint32_t lofs[2];
#pragma unroll
    for (int ld = 0; ld < 2; ++ld) {
        int slot  = (ld << 9) + tid;
        int row   = slot >> 3;           // 0..127 within half
        int chunk = slot & 7;
        int colb  = (chunk ^ (row & 7)) << 4;
        lofs[ld]  = slot << 4;
#pragma unroll
        for (int hf = 0; hf < 2; ++hf) {
            int arow = m0 + (hf << 7) + row;
            offA[ld][hf] = ((uint32_t)arow << 12) + colb;
            int br   = (hf << 7) + row;                    // B tile row 0..255
            int gate = (br >> 4) & 3;
            int hl   = ((br >> 6) << 4) + (br & 15);
            int wrow = (gate << 10) + h0 + hl;
            offB[ld][hf] = ((uint32_t)wrow << 12) + colb;
        }
    }
    const char* Ub = (const char*)U;     // row stride 4096 B
    const char* Wb = (const char*)W;     // row stride 4096 B
    char* AsB = (char*)As;
    char* BsB = (char*)Bs;

#define STG_A(hf, dbuf, ktt) do {                                              \
        g2l16(Ub + offA[0][hf] + ((ktt) << 7),                                 \
              AsB + ((dbuf) << 15) + ((hf) << 14) + lofs[0]);                  \
        g2l16(Ub + offA[1][hf] + ((ktt) << 7),                                 \
              AsB + ((dbuf) << 15) + ((hf) << 14) + lofs[1]);                  \
    } while (0)
#define STG_B(hf, dbuf, ktt) do {                                              \
        g2l16(Wb + offB[0][hf] + ((ktt) << 7),                                 \
              BsB + ((dbuf) << 15) + ((hf) << 14) + lofs[0]);                  \
        g2l16(Wb + offB[1][hf] + ((ktt) << 7),                                 \
              BsB + ((dbuf) << 15) + ((hf) << 14) + lofs[1]);                  \
    } while (0)

// fragment read: global chunk (ks*4+quad), swizzled by row&7 == lc&7
#define LDFRAG(BASEB, dbuf, row, ks)                                           \
    (*(const bf16x8*)((BASEB) + ((dbuf) << 15) + ((row) << 7) +                \
                      ((((((ks) << 2)) + quad) ^ (lc & 7)) << 4)))

#define MFMA_Q(MIBASE, NIBASE)                                                 \
    do {                                                                       \
        _Pragma("unroll")                                                      \
        for (int mi = 0; mi < 4; ++mi)                                         \
            _Pragma("unroll")                                                  \
            for (int ni = 0; ni < 2; ++ni)                                     \
                _Pragma("unroll")                                              \
                for (int ks = 0; ks < 2; ++ks)                                 \
                    acc[(MIBASE) + mi][(NIBASE) + ni] =                        \
                        __builtin_amdgcn_mfma_f32_16x16x32_bf16(               \
                            a_[mi][ks], b_[(NIBASE) + ni][ks],                 \
                            acc[(MIBASE) + mi][(NIBASE) + ni], 0, 0, 0);       \
    } while (0)

    f32x4 acc[8][4];
#pragma unroll
    for (int mi = 0; mi < 8; ++mi)
#pragma unroll
        for (int ni = 0; ni < 4; ++ni)
            acc[mi][ni] = (f32x4){0.f, 0.f, 0.f, 0.f};

    // ---- prologue: issue kt0 {Blo,Alo,Ahi,Bhi} + kt1 {Blo,Alo} (12 loads),
    // vmcnt(4): kt0 fully landed, kt1.{Blo,Alo} = 4 newest stay in flight
    // (same invariant as steady-state P4 exit).
    STG_B(0, 0, 0);
    STG_A(0, 0, 0);
    STG_A(1, 0, 0);
    STG_B(1, 0, 0);
    STG_B(0, 1, 1);
    STG_A(0, 1, 1);
    asm volatile("s_waitcnt vmcnt(4)" ::: "memory");

    const int rA0 = (wm << 7) + lc;      // A row base, mi-half 0
    const int rB0 = (wn << 6) + lc;      // B row base

    bf16x8 a_[4][2];                     // current A mi-half frags [mi&3][ks]
    bf16x8 b_[4][2];                     // all B frags for the K-tile [ni][ks]

#pragma clang loop unroll(disable)
    for (int kt = 0; kt < NKT; ++kt) {
        const int buf = kt & 1;

        // ---- P1: stage kt+1.A-hi | read a0 + all b | Q(0,0) ----
        __builtin_amdgcn_s_barrier();
        if (kt < NKT - 1) STG_A(1, buf ^ 1, kt + 1);
#pragma unroll
        for (int mi = 0; mi < 4; ++mi) {
            a_[mi][0] = LDFRAG(AsB, buf, rA0 + (mi << 4), 0);
            a_[mi][1] = LDFRAG(AsB, buf, rA0 + (mi << 4), 1);
        }
#pragma unroll
        for (int ni = 0; ni < 4; ++ni) {
            b_[ni][0] = LDFRAG(BsB, buf, rB0 + (ni << 4), 0);
            b_[ni][1] = LDFRAG(BsB, buf, rB0 + (ni << 4), 1);
        }
        __builtin_amdgcn_s_setprio(1);
        MFMA_Q(0, 0);
        __builtin_amdgcn_s_setprio(0);

        // ---- P2: stage kt+1.B-hi | Q(0,2) | issue a1 (flies into P3) ----
        __builtin_amdgcn_s_barrier();
        if (kt < NKT - 1) STG_B(1, buf ^ 1, kt + 1);
        __builtin_amdgcn_s_setprio(1);
        MFMA_Q(0, 2);
        __builtin_amdgcn_s_setprio(0);
#pragma unroll
        for (int mi = 0; mi < 4; ++mi) {
            a_[mi][0] = LDFRAG(AsB, buf, rA0 + 64 + (mi << 4), 0);
            a_[mi][1] = LDFRAG(AsB, buf, rA0 + 64 + (mi << 4), 1);
        }

        // ---- P3: stage kt+2.B-lo | Q(4,0) ----
        __builtin_amdgcn_s_barrier();
        if (kt < NKT - 2) STG_B(0, buf, kt + 2);
        __builtin_amdgcn_s_setprio(1);
        MFMA_Q(4, 0);
        __builtin_amdgcn_s_setprio(0);

        // ---- P4: stage kt+2.A-lo | Q(4,2) | counted vmcnt ----
        __builtin_amdgcn_s_barrier();
        if (kt < NKT - 2) STG_A(0, buf, kt + 2);
        __builtin_amdgcn_s_setprio(1);
        MFMA_Q(4, 2);
        __builtin_amdgcn_s_setprio(0);
        if (kt < NKT - 2) {
            asm volatile("s_waitcnt vmcnt(4)" ::: "memory");
        } else if (kt == NKT - 2) {
            asm volatile("s_waitcnt vmcnt(0)" ::: "memory");
        }
    }

    // ---- LSTM epilogue: C/D layout col=lane&15, row=quad*4+reg; ni == gate ----
    const int h = h0 + (wn << 4) + lc;
    float bias[4];
#pragma unroll
    for (int g = 0; g < 4; ++g) bias[g] = bb[(g << 10) + h];

    float* out_h = out;
    float* out_c = out + (size_t)B_DIM * H_DIM;
#pragma unroll
    for (int mi = 0; mi < 8; ++mi) {
#pragma unroll
        for (int r = 0; r < 4; ++r) {
            int brow  = m0 + (wm << 7) + (mi << 4) + (quad << 2) + r;
            size_t rb = (size_t)brow << 10;
            float zp = acc[mi][0][r] + bias[0];
            float ip = acc[mi][1][r] + bias[1];
            float fp = acc[mi][2][r] + bias[2];
            float op = acc[mi][3][r] + bias[3];
            float zz = tanh_fast(zp);
            float ii = sigm_fast(ip);
            float ff = sigm_fast(fp);
            float oo = sigm_fast(op);
            float cp = cprev[rb + h];
            float cn = ff * cp + ii * zz;
            float hn = oo * tanh_fast(cn);
            out_h[rb + h] = hn;
            out_c[rb + h] = cn;
        }
    }
}

extern "C" void kernel_launch(void* const* d_in, const int* in_sizes, int n_in,
                              void* d_out, int out_size, void* d_ws, size_t ws_size,
                              hipStream_t stream) {
    const float* x  = (const float*)d_in[0];
    const float* hp = (const float*)d_in[1];
    const float* cp = (const float*)d_in[2];
    const float* Wx = (const float*)d_in[3];
    const float* bx = (const float*)d_in[4];
    const float* Rh = (const float*)d_in[5];
    const float* bh = (const float*)d_in[6];

    // workspace: U 64 MiB | W 16 MiB | bb 16 KiB
    bf16*  U  = (bf16*)d_ws;
    bf16*  W  = (bf16*)((char*)d_ws + (size_t)67108864);
    float* bb = (float*)((char*)d_ws + (size_t)67108864 + 16777216);

    cvt_all<<<10240, 256, 0, stream>>>(x, hp, Wx, Rh, bx, bh, U, W, bb);
    lstm_fused<<<1024, 512, 0, stream>>>(U, W, bb, cp, (float*)d_out);
}